// Round 8
// baseline (330.030 us; speedup 1.0000x reference)
//
#include <hip/hip_runtime.h>
#include <math.h>

// NanoRAG: cosine-sim retrieval + top-8 + softmax fusion.
// K0: normalize queries, split into bf16 hi/lo -> ws.qh/ws.ql
// K1: split-bf16 MFMA GEMM, DBLK=128 docs/block, 4 waves split the q-dim.
//     A/B EXPERIMENT vs R6: doc loads are 4 rows x 256-B segments per
//     instruction (2 k-tiles staged per round) instead of 8 rows x 128-B.
//     Docs reg-staged, RNE-split once, shared via 4 LDS bf16 kt-planes
//     (72-B row stride). q streamed per-outer (L2-hot), FIFO vmcnt(8).
// K2a: partial merge 2048 lists -> 8 chunk lists per q (512 blocks)
// K2b: final merge 64 -> top-8, softmax, gather+fuse -> d_out
//
// d_out layout (fp32): fused[64*384], scores[64*8], idx[64*8]

#define EMBED 384
#define NDOCS 262144
#define BATCH 64
#define TOPK 8
#define DBLK 128
#define NBLK (NDOCS / DBLK)   // 2048
#define EPSN 1e-8f
#define SCW 132
// bf16 kt-planes: row stride 72 B, plane 128*72 = 9216 B
#define PL_HI1 9216u
#define PL_LO  18432u
#define RN_OFF 36864

typedef __attribute__((ext_vector_type(8))) short bf16x8;
typedef __attribute__((ext_vector_type(4))) float f32x4;

// register-resident sorted top-8 insertion (all indices compile-time)
#define INS8(s_, i_) do {                                                     \
    if ((s_) > ts[7] || ((s_) == ts[7] && (i_) < ti[7])) {                    \
        ts[7] = (s_); ti[7] = (i_);                                           \
        _Pragma("unroll")                                                     \
        for (int r_ = 7; r_ > 0; --r_) {                                      \
            bool sw_ = (ts[r_] > ts[r_-1]) ||                                 \
                       (ts[r_] == ts[r_-1] && ti[r_] < ti[r_-1]);             \
            float a_ = ts[r_-1]; int b_ = ti[r_-1];                           \
            ts[r_-1] = sw_ ? ts[r_] : a_;  ti[r_-1] = sw_ ? ti[r_] : b_;      \
            ts[r_]   = sw_ ? a_ : ts[r_];  ti[r_]   = sw_ ? b_ : ti[r_];      \
        }                                                                     \
    }                                                                         \
} while (0)

// saddr-form global load: 32-bit per-lane voffset + uniform SGPR base
template<int OFF>
__device__ __forceinline__ int4 gload_s(unsigned voff, const void* sbase) {
    int4 r;
    asm volatile("global_load_dwordx4 %0, %1, %2 offset:%3"
                 : "=v"(r) : "v"(voff), "s"(sbase), "i"(OFF) : "memory");
    return r;
}

__device__ __forceinline__ int4 dsread16(unsigned a) {
    int4 r;
    asm volatile("ds_read_b128 %0, %1" : "=v"(r) : "v"(a) : "memory");
    return r;
}

// Manual RNE bf16 split: f ~= hi + lo, |err| <= 2^-18|f|. PROVEN numerics
// (R2/R3/R6/R7 absmax 3e-5). Do NOT use v_cvt_pk_bf16_f32 (R4 index flip).
#define SPB(F, H, O) {                                                        \
    unsigned u_ = __float_as_uint(F);                                         \
    H = (u_ + 0x7fffu + ((u_ >> 16) & 1u)) >> 16;                             \
    float r_ = (F) - __uint_as_float((H) << 16);                              \
    unsigned v_ = __float_as_uint(r_);                                        \
    O = (v_ + 0x7fffu + ((v_ >> 16) & 1u)) >> 16;                             \
}

// split chunk C (4 consecutive k of one row) -> packed hi/lo uint2 + sumsq
#define SPLIT4(C) {                                                           \
    f32x4 f_ = *(f32x4*)&ld[C];                                               \
    nacc[C] = fmaf(f_[0], f_[0], fmaf(f_[1], f_[1],                           \
              fmaf(f_[2], f_[2], fmaf(f_[3], f_[3], nacc[C]))));              \
    unsigned h0_, h1_, h2_, h3_, o0_, o1_, o2_, o3_;                          \
    SPB(f_[0], h0_, o0_); SPB(f_[1], h1_, o1_);                               \
    SPB(f_[2], h2_, o2_); SPB(f_[3], h3_, o3_);                               \
    sh[C].x = (h0_ & 0xffffu) | (h1_ << 16);                                  \
    sh[C].y = (h2_ & 0xffffu) | (h3_ << 16);                                  \
    sl[C].x = (o0_ & 0xffffu) | (o1_ << 16);                                  \
    sl[C].y = (o2_ & 0xffffu) | (o3_ << 16);                                  \
}

__global__ void qprep_kernel(const float* __restrict__ q,
                             unsigned short* __restrict__ qh,
                             unsigned short* __restrict__ ql) {
    const int row = blockIdx.x;     // 64 blocks
    const int lane = threadIdx.x;   // 64 threads
    float v[6];
    float s = 0.f;
#pragma unroll
    for (int i = 0; i < 6; ++i) {
        v[i] = q[row * EMBED + lane + 64 * i];
        s = fmaf(v[i], v[i], s);
    }
#pragma unroll
    for (int off = 32; off > 0; off >>= 1) s += __shfl_xor(s, off);
    float rinv = 1.0f / (sqrtf(s) + EPSN);
#pragma unroll
    for (int i = 0; i < 6; ++i) {
        float f = v[i] * rinv;
        unsigned h, lo;
        SPB(f, h, lo);
        qh[row * EMBED + lane + 64 * i] = (unsigned short)h;
        ql[row * EMBED + lane + 64 * i] = (unsigned short)lo;
    }
}

__global__ __launch_bounds__(256, 2) void score_topk_kernel(
        const float* __restrict__ docs,
        const unsigned short* __restrict__ qh,
        const unsigned short* __restrict__ ql,
        float* __restrict__ pscore, int* __restrict__ pidx) {
    // LDS k-loop: hi kt0 @0, hi kt1 @9216, lo kt0 @18432, lo kt1 @27648
    // (128 rows x 32 k bf16, row stride 72 B). Epilogue overlays S[64][132]
    // @0 (33.8 KB); RN[128] @36864.
    __shared__ __align__(16) char smem[37376];
    float* S  = (float*)smem;
    float* RN = (float*)(smem + RN_OFF);

    const int tid = threadIdx.x;
    const int l   = tid & 63;
    const int wv  = tid >> 6;          // wave: q-tile wv, stages rows wv*32..+31
    const int d0 = blockIdx.x * DBLK;
    const unsigned bse = (unsigned)(uintptr_t)smem;

    f32x4 acc[8];                      // 16 q x 128 docs (8 doc-strips)
#pragma unroll
    for (int s = 0; s < 8; ++s) acc[s] = (f32x4){0.f, 0.f, 0.f, 0.f};
    float nacc[8];
#pragma unroll
    for (int c = 0; c < 8; ++c) nacc[c] = 0.f;

    // doc voffsets: chunk c: lane l -> row wv*32 + 4c + (l>>4), byte 16(l&15)
    // => 4 segments x 256 B per instruction (the A/B variable vs R6's 8x128B)
    unsigned voff[8];
#pragma unroll
    for (int c = 0; c < 8; ++c)
        voff[c] = (unsigned)((wv * 32 + 4 * c + (l >> 4)) * 1536)
                + (unsigned)((l & 15) * 16);
    const float* dblk = docs + (size_t)d0 * EMBED;   // uniform SGPR base

    // q voffset: lane l -> q-row wv*16 + (l&15), k-slice (l>>4)*8 (bf16)
    const unsigned voffq = (unsigned)((wv * 16 + (l & 15)) * (EMBED * 2)
                                      + (l >> 4) * 16);

    // LDS write base: kt = (l&15)>>3, row = wv*32 + (l>>4), kq-byte (l&7)*8
    const unsigned whbase = ((unsigned)((l & 15) >> 3)) * PL_HI1
                          + (unsigned)((wv * 32 + (l >> 4)) * 72 + (l & 7) * 8);
    // ds_read frag base: step i (kt=i>>3, strip s=i&7):
    //   addr = kt*9216 + (s*16 + (l&15))*72 + (l>>4)*16
    const unsigned rbase = (unsigned)((l & 15) * 72 + (l >> 4) * 16);

    int4 ld[8];
    uint2 sh[8], sl[8];
    int4 qf[2][2];                     // [kt][hi/lo]

    // prologue: outer-0 docs
#pragma unroll
    for (int c = 0; c < 8; ++c) ld[c] = gload_s<0>(voff[c], dblk);
    asm volatile("s_waitcnt vmcnt(0)" ::: "memory");
    __builtin_amdgcn_sched_barrier(0);
#pragma unroll
    for (int c = 0; c < 8; ++c) SPLIT4(c);

#define KITER(O, LAST) {                                                       \
    __syncthreads();                       /* prior tile reads done */         \
    _Pragma("unroll")                                                          \
    for (int c = 0; c < 8; ++c) {                                              \
        *(uint2*)(smem + whbase + 288u * c) = sh[c];                           \
        *(uint2*)(smem + PL_LO + whbase + 288u * c) = sl[c];                   \
    }                                                                          \
    __syncthreads();                       /* tile O ready */                  \
    qf[0][0] = gload_s<(O) * 128>(voffq, qh);                                  \
    qf[0][1] = gload_s<(O) * 128>(voffq, ql);                                  \
    qf[1][0] = gload_s<(O) * 128 + 64>(voffq, qh);                             \
    qf[1][1] = gload_s<(O) * 128 + 64>(voffq, ql);                             \
    if (!(LAST)) {                                                             \
        _Pragma("unroll")                                                      \
        for (int c = 0; c < 8; ++c)                                            \
            ld[c] = gload_s<((O) + 1) * 256>(voff[c], dblk);                   \
    }                                                                          \
    asm volatile("s_waitcnt vmcnt(%0)" :: "i"((LAST) ? 0 : 8) : "memory");     \
    __builtin_amdgcn_sched_barrier(0);                                         \
    {                                                                          \
        int4 fh0, fl0, fh1, fl1;                                               \
        fh0 = dsread16(bse + rbase);                                           \
        fl0 = dsread16(bse + rbase + PL_LO);                                   \
        _Pragma("unroll")                                                      \
        for (int i = 0; i < 16; ++i) {                                         \
            if (i < 15) {                                                      \
                unsigned na = bse + (unsigned)(((i + 1) >> 3) * 9216)          \
                            + (unsigned)(((i + 1) & 7) * 16 * 72) + rbase;     \
                fh1 = dsread16(na);                                            \
                fl1 = dsread16(na + PL_LO);                                    \
                asm volatile("s_waitcnt lgkmcnt(2)" ::: "memory");             \
            } else {                                                           \
                asm volatile("s_waitcnt lgkmcnt(0)" ::: "memory");             \
            }                                                                  \
            __builtin_amdgcn_sched_barrier(0);                                 \
            bf16x8 bh = *(bf16x8*)&fh0, bl = *(bf16x8*)&fl0;                   \
            bf16x8 ah = *(bf16x8*)&qf[i >> 3][0];                              \
            bf16x8 al = *(bf16x8*)&qf[i >> 3][1];                              \
            acc[i & 7] = __builtin_amdgcn_mfma_f32_16x16x32_bf16(ah, bh, acc[i & 7], 0, 0, 0); \
            acc[i & 7] = __builtin_amdgcn_mfma_f32_16x16x32_bf16(al, bh, acc[i & 7], 0, 0, 0); \
            acc[i & 7] = __builtin_amdgcn_mfma_f32_16x16x32_bf16(ah, bl, acc[i & 7], 0, 0, 0); \
            fh0 = fh1; fl0 = fl1;                                              \
        }                                                                      \
    }                                                                          \
    if (!(LAST)) {                                                             \
        asm volatile("s_waitcnt vmcnt(0)" ::: "memory");                       \
        __builtin_amdgcn_sched_barrier(0);                                     \
        _Pragma("unroll")                                                      \
        for (int c = 0; c < 8; ++c) SPLIT4(c);                                 \
    }                                                                          \
}

    KITER(0, 0) KITER(1, 0) KITER(2, 0) KITER(3, 0) KITER(4, 0) KITER(5, 1)
#undef KITER

    // doc norms: lane l holds k-partial for row wv*32+4c+(l>>4);
    // reduce across the 16-lane (l&15) group
#pragma unroll
    for (int c = 0; c < 8; ++c) {
        float t = nacc[c];
        t += __shfl_xor(t, 1);
        t += __shfl_xor(t, 2);
        t += __shfl_xor(t, 4);
        t += __shfl_xor(t, 8);
        if ((l & 15) == 0)
            RN[wv * 32 + 4 * c + (l >> 4)] = 1.0f / (sqrtf(t) + EPSN);
    }
    __syncthreads();   // plane reads done + RN visible; safe to overlay S

    // park normalized scores: q-row = wv*16 + (l>>4)*4 + j, col = s*16 + (l&15)
#pragma unroll
    for (int s = 0; s < 8; ++s) {
        float rn = RN[s * 16 + (l & 15)];
#pragma unroll
        for (int j = 0; j < 4; ++j)
            S[(wv * 16 + (l >> 4) * 4 + j) * SCW + s * 16 + (l & 15)] = acc[s][j] * rn;
    }
    __syncthreads();

    // top-8: thread t scans query t&63 over quarter (t>>6)*32..+31, staggered
    float ts[8]; int ti[8];
#pragma unroll
    for (int r = 0; r < 8; ++r) { ts[r] = -3.402823466e38f; ti[r] = 0x7fffffff; }
    const int q = tid & 63, qa = tid >> 6;
    for (int ii = 0; ii < 32; ++ii) {
        int d = qa * 32 + ((ii + q) & 31);
        float sc = S[q * SCW + d];
        INS8(sc, d0 + d);
    }
    __syncthreads();   // all S reads done; safe to overwrite
#pragma unroll
    for (int r = 0; r < 8; ++r) {
        S[(qa * 64 + q) * 8 + r] = ts[r];
        S[2048 + (qa * 64 + q) * 8 + r] = __int_as_float(ti[r]);
    }
    __syncthreads();
    if (tid < 64) {
#pragma unroll
        for (int r = 0; r < 8; ++r) { ts[r] = -3.402823466e38f; ti[r] = 0x7fffffff; }
        for (int a = 0; a < 4; ++a) {
#pragma unroll
            for (int r = 0; r < 8; ++r) {
                float s2 = S[(a * 64 + q) * 8 + r];
                int i2 = __float_as_int(S[2048 + (a * 64 + q) * 8 + r]);
                INS8(s2, i2);
            }
        }
        size_t o = ((size_t)q * NBLK + blockIdx.x) * TOPK;
        *(float4*)&pscore[o]     = make_float4(ts[0], ts[1], ts[2], ts[3]);
        *(float4*)&pscore[o + 4] = make_float4(ts[4], ts[5], ts[6], ts[7]);
        *(int4*)&pidx[o]     = make_int4(ti[0], ti[1], ti[2], ti[3]);
        *(int4*)&pidx[o + 4] = make_int4(ti[4], ti[5], ti[6], ti[7]);
    }
}

// stage A: block (q, c) merges lists c*256..c*256+255 -> one top-8 chunk list
__global__ __launch_bounds__(256) void merge_a_kernel(
        const float* __restrict__ pscore, const int* __restrict__ pidx,
        float* __restrict__ cs, int* __restrict__ ci) {
    const int q = blockIdx.x >> 3;
    const int c = blockIdx.x & 7;
    const int tid = threadIdx.x;
    __shared__ float ls[2048];
    __shared__ int   li[2048];
    __shared__ float ls2[512];
    __shared__ int   li2[512];
    __shared__ float ls3[64];
    __shared__ int   li3[64];

    {
        size_t o = ((size_t)q * NBLK + c * 256 + tid) * TOPK;
        float4 s0 = *(const float4*)&pscore[o];
        float4 s1 = *(const float4*)&pscore[o + 4];
        int4 i0 = *(const int4*)&pidx[o];
        int4 i1 = *(const int4*)&pidx[o + 4];
        ls[tid * 8 + 0] = s0.x; ls[tid * 8 + 1] = s0.y;
        ls[tid * 8 + 2] = s0.z; ls[tid * 8 + 3] = s0.w;
        ls[tid * 8 + 4] = s1.x; ls[tid * 8 + 5] = s1.y;
        ls[tid * 8 + 6] = s1.z; ls[tid * 8 + 7] = s1.w;
        li[tid * 8 + 0] = i0.x; li[tid * 8 + 1] = i0.y;
        li[tid * 8 + 2] = i0.z; li[tid * 8 + 3] = i0.w;
        li[tid * 8 + 4] = i1.x; li[tid * 8 + 5] = i1.y;
        li[tid * 8 + 6] = i1.z; li[tid * 8 + 7] = i1.w;
    }
    __syncthreads();

    float ts[8]; int ti[8];
    if (tid < 64) {
#pragma unroll
        for (int r = 0; r < 8; ++r) { ts[r] = -3.402823466e38f; ti[r] = 0x7fffffff; }
        for (int e = 0; e < 32; ++e) {
            int k = tid + e * 64;
            float s = ls[k]; int gi = li[k];
            INS8(s, gi);
        }
#pragma unroll
        for (int r = 0; r < 8; ++r) { ls2[tid * 8 + r] = ts[r]; li2[tid * 8 + r] = ti[r]; }
    }
    __syncthreads();
    if (tid < 8) {
#pragma unroll
        for (int r = 0; r < 8; ++r) { ts[r] = -3.402823466e38f; ti[r] = 0x7fffffff; }
        for (int e = 0; e < 64; ++e) {
            int k = tid + e * 8;
            float s = ls2[k]; int gi = li2[k];
            INS8(s, gi);
        }
#pragma unroll
        for (int r = 0; r < 8; ++r) { ls3[tid * 8 + r] = ts[r]; li3[tid * 8 + r] = ti[r]; }
    }
    __syncthreads();
    if (tid == 0) {
#pragma unroll
        for (int r = 0; r < 8; ++r) { ts[r] = -3.402823466e38f; ti[r] = 0x7fffffff; }
        for (int e = 0; e < 64; ++e) {
            float s = ls3[e]; int gi = li3[e];
            INS8(s, gi);
        }
        size_t o = (size_t)(q * 8 + c) * TOPK;
#pragma unroll
        for (int r = 0; r < 8; ++r) { cs[o + r] = ts[r]; ci[o + r] = ti[r]; }
    }
}

// stage B: final merge (64 candidates), softmax, gather+fuse
__global__ __launch_bounds__(256) void merge_b_kernel(
        const float* __restrict__ docs, const float* __restrict__ cs,
        const int* __restrict__ ci, float* __restrict__ out) {
    const int q = blockIdx.x;
    const int tid = threadIdx.x;
    __shared__ int   fi[TOPK];
    __shared__ float wr[TOPK];

    if (tid == 0) {
        float ts[8]; int ti[8];
#pragma unroll
        for (int r = 0; r < 8; ++r) { ts[r] = -3.402823466e38f; ti[r] = 0x7fffffff; }
        for (int e = 0; e < 64; ++e) {
            float s = cs[q * 64 + e]; int gi = ci[q * 64 + e];
            INS8(s, gi);
        }
        float m = ts[0];
        float w[8]; float sum = 0.f;
#pragma unroll
        for (int r = 0; r < 8; ++r) { w[r] = expf(ts[r] - m); sum += w[r]; }
        float rs = 1.0f / sum;
#pragma unroll
        for (int r = 0; r < 8; ++r) {
            fi[r] = ti[r];
            wr[r] = w[r] * rs;
            out[BATCH * EMBED + q * TOPK + r] = ts[r];
            out[BATCH * EMBED + BATCH * TOPK + q * TOPK + r] = (float)ti[r];
        }
    }
    __syncthreads();

    int lane = tid & 63, wave = tid >> 6;
    for (int r = wave; r < TOPK; r += 4) {
        const float* dp = docs + (size_t)fi[r] * EMBED;
        float s = 0.f;
#pragma unroll
        for (int i = 0; i < 6; ++i) { float v = dp[lane + 64 * i]; s = fmaf(v, v, s); }
#pragma unroll
        for (int off = 32; off > 0; off >>= 1) s += __shfl_xor(s, off);
        if (lane == 0) wr[r] = wr[r] / (sqrtf(s) + EPSN);
    }
    __syncthreads();

    for (int dim = tid; dim < EMBED; dim += 256) {
        float a = 0.f;
#pragma unroll
        for (int r = 0; r < 8; ++r)
            a += wr[r] * docs[(size_t)fi[r] * EMBED + dim];
        out[q * EMBED + dim] = a;
    }
}

extern "C" void kernel_launch(void* const* d_in, const int* in_sizes, int n_in,
                              void* d_out, int out_size, void* d_ws, size_t ws_size,
                              hipStream_t stream) {
    const float* query = (const float*)d_in[0];
    const float* docs  = (const float*)d_in[1];
    float* out = (float*)d_out;

    char* ws = (char*)d_ws;
    unsigned short* qh = (unsigned short*)ws;                       // 48 KiB
    unsigned short* ql = (unsigned short*)(ws + 49152);             // 48 KiB
    float* pscore = (float*)(ws + 98304);                           // 4 MiB
    int*   pidx   = (int*)(ws + 98304 + (size_t)NBLK * BATCH * TOPK * 4);
    char*  ws3    = ws + 98304 + 2 * (size_t)NBLK * BATCH * TOPK * 4;
    float* cs     = (float*)ws3;                                    // 16 KiB
    int*   ci     = (int*)(ws3 + BATCH * 8 * TOPK * 4);

    qprep_kernel<<<64, 64, 0, stream>>>(query, qh, ql);
    score_topk_kernel<<<NBLK, 256, 0, stream>>>(docs, qh, ql, pscore, pidx);
    merge_a_kernel<<<BATCH * 8, 256, 0, stream>>>(pscore, pidx, cs, ci);
    merge_b_kernel<<<BATCH, 256, 0, stream>>>(docs, cs, ci, out);
}